// Round 10
// baseline (356.087 us; speedup 1.0000x reference)
//
#include <hip/hip_runtime.h>
#include <hip/hip_fp16.h>
#include <math.h>

// ---------------------------------------------------------------------------
// Net_37512244363273: 5-level edge-conditioned graph conv + voxel pooling + FC
// Round 25: revert to R22 (best, 338.9us; R23/R24 A/B showed both perm-pool0
// [+12us] and wave-convs [+9.5us] were regressions) + k1 occupancy fix.
// R24 profile: k1 = 45us @ occ 22%, VALU 11%, HBM 12% -- latency-bound via
// LDS cap (38.9KB/block -> 4 blocks/CU). Tiles 2048->1024 edges (NT0=1024,
// NT1=256): LDS 21.5KB -> 7 blocks/CU (~87% occ ceiling). Reserve atomics
// double to 262K (~+3-6us absorbed); pay2 runs 8->4 (still 64B-friendly).
// Pipeline: memset | k1 part0+part1+hstats+hist | k2 conv0c+bs1scan+scanC+
// scanC3+wstats | k3 scatter+bucket1 | k4 pool0 | k5 conv1 | k6-8 conv2-4 |
// k9 fc.  9 dispatches + memset.
// ---------------------------------------------------------------------------

#define NT0   1024                 // part0 tiles (1024 edges)
#define TSZ0  1024
#define NBK0  256                  // L0 buckets (dst>>8, 256 nodes each)
#define CAP0  4608                 // per-bucket capacity (avg 4096 + 8 sigma)
#define NT1   256                  // part1 tiles (1024 edges)
#define TSZ1  1024
#define NBK1  256                  // L1 buckets (dst>>6, 64 nodes each)
#define CAP1  1280                 // per-bucket capacity (avg 1024 + 8 sigma)

__device__ __forceinline__ float ftanh(float x) {
    float e = __expf(2.f * x);
    return 1.f - 2.f / (e + 1.f);
}

// order-preserving float<->uint (monotone): enables atomicMax-based fmax
__device__ __forceinline__ unsigned fenc(float f) {
    int b = __float_as_int(f);
    return (b < 0) ? ~(unsigned)b : ((unsigned)b | 0x80000000u);
}
__device__ __forceinline__ float fdec(unsigned u) {
    int b = (u & 0x80000000u) ? (int)(u & 0x7fffffffu) : ~(int)u;
    return __int_as_float(b);
}

// decode element i of a pooled raw row [CI-3 max-enc | 3 possum | 1 cnt]
__device__ __forceinline__ float row_val(const unsigned* __restrict__ row,
                                         int i, int CI) {
    float cn = __uint_as_float(row[CI]);
    if (i < CI - 3) return (cn == 0.f) ? 0.f : fdec(row[i]);
    return __uint_as_float(row[i]) / fmaxf(cn, 1.f);
}

struct Seg4 {                       // edge segs L2-4 + cluster0 seg
    const int* idx[4];
    int*       cnt[4];
    int*       rp [4];
    int*       out[4];
    int        n  [4];
    int        nb [4];
    int        tstart[5];
};

struct GA {
    // inputs
    const int *src0, *dst0; const float* ea0;
    const int *src1, *dst1; const float* ea1;
    const float *x0, *pos0;
    const int* cluster[5];
    const float *w1[5], *b1[5], *w2[5], *b2[5], *root[5], *bias[5];
    const int* srcE[3]; const float* eaE[3];
    const float *fc_w, *fc_b;
    // workspace
    int *bcnt, *bcnt1;              // [NBK0]/[NBK1] reservation counters
    float4 *pay2, *pay1, *rec1;
    float *y0, *xn0;
    unsigned* raw[5];               // pooled rows for levels 1-4
    float *H, *sq;
    int *bs1, *rp1;
    Seg4 sg;
    float* out;
    int hb0[4], hsB;                // hstats (levels 2-4 only)
};

// ---------------------------------------------------------------------------
// K1: part0 (1024) | part1 (256) | hstats L2-4 (42) | hist 4 segs (148)
// LDS: stg 16KB + bkb 1KB + 4x1KB scans = 21.5KB -> 7 blocks/CU.
// ---------------------------------------------------------------------------
__global__ __launch_bounds__(256) void k1_fuseA(GA A)
{
    __shared__ float4 stg[TSZ0];                   // 16KB
    __shared__ unsigned char bkb[TSZ0];            // 1KB
    __shared__ int hb_[256], gb_[256], ls_[256], cu_[256];

    int B = blockIdx.x, t = threadIdx.x;

    if (B < NT0) {                                 // ---- part0-append ----
        hb_[t] = 0;
        __syncthreads();
        int base = B * TSZ0 + t;
        int dreg[4];
        #pragma unroll
        for (int k = 0; k < 4; k++) {
            dreg[k] = A.dst0[base + k * 256];
            atomicAdd(&hb_[dreg[k] >> 8], 1);
        }
        __syncthreads();
        int c = hb_[t];
        gb_[t] = c ? atomicAdd(&A.bcnt[t], c) : 0;
        ls_[t] = c;
        __syncthreads();
        for (int d = 1; d < 256; d <<= 1) {
            int u = (t >= d) ? ls_[t - d] : 0;
            __syncthreads();
            ls_[t] += u;
            __syncthreads();
        }
        int ex = ls_[t] - c;
        ls_[t] = ex;
        cu_[t] = ex;
        __syncthreads();

        float w1r[15], b1r[5];
        #pragma unroll
        for (int i = 0; i < 15; i++) w1r[i] = A.w1[0][i];
        #pragma unroll
        for (int i = 0; i < 5; i++)  b1r[i] = A.b1[0][i];
        float acc[20];
        #pragma unroll
        for (int i = 0; i < 20; i++) acc[i] = 0.f;
        #pragma unroll
        for (int k = 0; k < 4; k++) {
            int i = base + k * 256;
            int d = dreg[k];
            int sv = A.src0[i];
            float e0 = A.ea0[i * 3], e1 = A.ea0[i * 3 + 1], e2 = A.ea0[i * 3 + 2];
            float h[5];
            #pragma unroll
            for (int q = 0; q < 5; q++)
                h[q] = ftanh(e0 * w1r[q] + e1 * w1r[5 + q] + e2 * w1r[10 + q] + b1r[q]);
            int p = 5;
            #pragma unroll
            for (int q = 0; q < 5; q++) {
                acc[q] += h[q];
                #pragma unroll
                for (int q2 = q; q2 < 5; q2++) acc[p++] += h[q] * h[q2];
            }
            float xv = A.x0[sv];
            union HU { __half2 h2; float f; } p01, p23;
            p01.h2 = __floats2half2_rn(h[0], h[1]);
            p23.h2 = __floats2half2_rn(h[2], h[3]);
            unsigned wbits = ((unsigned)d << 16) |
                             (unsigned)__half_as_ushort(__float2half_rn(h[4]));
            int bk = d >> 8;
            int ps = atomicAdd(&cu_[bk], 1);
            stg[ps] = make_float4(xv, p01.f, p23.f, __uint_as_float(wbits));
            bkb[ps] = (unsigned char)bk;
        }
        __syncthreads();
        #pragma unroll
        for (int k = 0; k < 4; k++) {              // coalesced-run write-out
            int p = k * 256 + t;
            int bk = bkb[p];
            int off = gb_[bk] + (p - ls_[bk]);
            if (off < CAP0)
                A.pay2[(size_t)bk * CAP0 + off] = stg[p];
        }
        __syncthreads();
        float* red = (float*)cu_;
        int wid = t >> 6, lane = t & 63;
        #pragma unroll
        for (int v = 0; v < 20; v++) {
            float s = acc[v];
            #pragma unroll
            for (int o = 32; o; o >>= 1) s += __shfl_down(s, o);
            if (lane == 0) red[wid * 20 + v] = s;
        }
        __syncthreads();
        if (t < 20)
            atomicAdd(&A.H[t], red[t] + red[20 + t] + red[40 + t] + red[60 + t]);
        return;
    }
    B -= NT0;
    if (B < NT1) {                                 // ---- part1-append ----
        hb_[t] = 0;
        __syncthreads();
        int base = B * TSZ1 + t;
        int dreg[4];
        #pragma unroll
        for (int k = 0; k < 4; k++) {
            dreg[k] = A.dst1[base + k * 256];
            atomicAdd(&hb_[dreg[k] >> 6], 1);
        }
        __syncthreads();
        int c = hb_[t];
        gb_[t] = c ? atomicAdd(&A.bcnt1[t], c) : 0;
        ls_[t] = c;
        __syncthreads();
        for (int d = 1; d < 256; d <<= 1) {
            int u = (t >= d) ? ls_[t - d] : 0;
            __syncthreads();
            ls_[t] += u;
            __syncthreads();
        }
        int ex = ls_[t] - c;
        ls_[t] = ex;
        cu_[t] = ex;
        __syncthreads();

        float w1r[15], b1r[5];
        #pragma unroll
        for (int i = 0; i < 15; i++) w1r[i] = A.w1[1][i];
        #pragma unroll
        for (int i = 0; i < 5; i++)  b1r[i] = A.b1[1][i];
        float acc[20];
        #pragma unroll
        for (int i = 0; i < 20; i++) acc[i] = 0.f;
        #pragma unroll
        for (int k = 0; k < 4; k++) {
            int i = base + k * 256;
            int d = dreg[k];
            int sv = A.src1[i];
            float e0 = A.ea1[i * 3], e1 = A.ea1[i * 3 + 1], e2 = A.ea1[i * 3 + 2];
            float h[5];
            #pragma unroll
            for (int q = 0; q < 5; q++)
                h[q] = ftanh(e0 * w1r[q] + e1 * w1r[5 + q] + e2 * w1r[10 + q] + b1r[q]);
            int p = 5;
            #pragma unroll
            for (int q = 0; q < 5; q++) {
                acc[q] += h[q];
                #pragma unroll
                for (int q2 = q; q2 < 5; q2++) acc[p++] += h[q] * h[q2];
            }
            int bk = d >> 6;
            int ps = atomicAdd(&cu_[bk], 1);
            stg[ps] = make_float4(__int_as_float((d << 16) | sv), e0, e1, e2);
            bkb[ps] = (unsigned char)bk;
        }
        __syncthreads();
        #pragma unroll
        for (int k = 0; k < 4; k++) {
            int p = k * 256 + t;
            int bk = bkb[p];
            int off = gb_[bk] + (p - ls_[bk]);
            if (off < CAP1)
                A.pay1[(size_t)bk * CAP1 + off] = stg[p];
        }
        __syncthreads();
        float* red = (float*)cu_;
        int wid = t >> 6, lane = t & 63;
        #pragma unroll
        for (int v = 0; v < 20; v++) {
            float s = acc[v];
            #pragma unroll
            for (int o = 32; o; o >>= 1) s += __shfl_down(s, o);
            if (lane == 0) red[wid * 20 + v] = s;
        }
        __syncthreads();
        if (t < 20)
            atomicAdd(&A.H[20 + t], red[t] + red[20 + t] + red[40 + t] + red[60 + t]);
        return;
    }
    B -= NT1;
    if (B < A.hsB) {                               // ---- hstats (L2-4) ----
        const int K = 8;
        int j = 0;
        while (j < 2 && B >= A.hb0[j + 1]) j++;
        int bloc = B - A.hb0[j];
        const float* ea = A.eaE[j];
        const float* w1p = A.w1[j + 2];
        const float* b1p = A.b1[j + 2];
        static const int EJ[3] = {65536, 16384, 4096};
        int Ej = EJ[j];
        float w1r[15], b1r[5];
        #pragma unroll
        for (int i = 0; i < 15; i++) w1r[i] = w1p[i];
        #pragma unroll
        for (int i = 0; i < 5; i++)  b1r[i] = b1p[i];
        float acc[20];
        #pragma unroll
        for (int i = 0; i < 20; i++) acc[i] = 0.f;
        int base = bloc * 256 * K + t;
        for (int it = 0; it < K; it++) {
            int e = base + it * 256;
            if (e < Ej) {
                float e0 = ea[e * 3], e1 = ea[e * 3 + 1], e2 = ea[e * 3 + 2];
                float h[5];
                #pragma unroll
                for (int q = 0; q < 5; q++)
                    h[q] = ftanh(e0 * w1r[q] + e1 * w1r[5 + q] + e2 * w1r[10 + q] + b1r[q]);
                int p = 5;
                #pragma unroll
                for (int q = 0; q < 5; q++) {
                    acc[q] += h[q];
                    #pragma unroll
                    for (int q2 = q; q2 < 5; q2++) acc[p++] += h[q] * h[q2];
                }
            }
        }
        float* red = (float*)hb_;
        int wid = t >> 6, lane = t & 63;
        #pragma unroll
        for (int v = 0; v < 20; v++) {
            float s = acc[v];
            #pragma unroll
            for (int o = 32; o; o >>= 1) s += __shfl_down(s, o);
            if (lane == 0) red[wid * 20 + v] = s;
        }
        __syncthreads();
        if (t < 20)
            atomicAdd(&A.H[(j + 2) * 20 + t],
                      red[t] + red[20 + t] + red[40 + t] + red[60 + t]);
        return;
    }
    B -= A.hsB;
    {                                              // ---- hist (4 segs) ----
        int s = 0;
        while (s < 3 && B >= A.sg.tstart[s + 1]) s++;
        int i0 = (B - A.sg.tstart[s]) * 1024;
        const int* idx = A.sg.idx[s];
        int* cnt = A.sg.cnt[s];
        int n = A.sg.n[s];
        #pragma unroll
        for (int j = 0; j < 4; j++) {
            int i = i0 + j * 256 + t;
            if (i < n) atomicAdd(&cnt[idx[i]], 1);
        }
    }
}

// ---------------------------------------------------------------------------
// K2: conv0c v2 (256) | bs1scan (1) | scanC segs 0-2 (3) | scanC3 (1) |
//     wstats (5).  LDS pool 34KB (union across roles).
// ---------------------------------------------------------------------------
__global__ __launch_bounds__(256) void k2_fuseB(GA A)
{
    __shared__ alignas(16) char poolc[34048];
    int B = blockIdx.x, t = threadIdx.x;

    if (B < NBK0) {                                // ---- conv0c v2 ----
        float4* stg = (float4*)poolc;                          // 16KB
        float*  Sx  = (float*)(poolc + 16384);                 // 7KB
        unsigned char* key = (unsigned char*)(poolc + 23552);  // 1KB
        short* inv = (short*)(poolc + 24576);                  // 2KB
        int* hist = (int*)(poolc + 26624);
        int* st   = (int*)(poolc + 27648);
        int* cur  = (int*)(poolc + 28672);
        float* wsm = (float*)(poolc + 29696);                  // 96 floats

        if (t < 60) wsm[t] = A.w2[0][t];
        else if (t >= 64  && t < 76)  wsm[60 + t - 64]  = A.b2[0][t - 64];
        else if (t >= 128 && t < 140) wsm[72 + t - 128] = A.root[0][t - 128];
        else if (t >= 192 && t < 204) wsm[84 + t - 192] = A.bias[0][t - 192];

        int n = A.bcnt[B];
        if (n > CAP0) n = CAP0;
        size_t base = (size_t)B * CAP0;
        float s0 = 0.f, s1 = 0.f, s2 = 0.f, s3 = 0.f, s4 = 0.f, s5 = 0.f, dg = 0.f;

        for (int c0 = 0; c0 < n; c0 += 1024) {
            int cn = min(1024, n - c0);
            hist[t] = 0;
            __syncthreads();
            #pragma unroll
            for (int k = 0; k < 4; k++) {          // load + hist (1 atomic/rec)
                int j = k * 256 + t;
                if (j < cn) {
                    float4 R = A.pay2[base + c0 + j];
                    stg[j] = R;
                    int rel = (int)(__float_as_uint(R.w) >> 16) & 255;
                    key[j] = (unsigned char)rel;
                    atomicAdd(&hist[rel], 1);
                }
            }
            __syncthreads();
            int h = hist[t];                       // block scan
            int acc = h;
            st[t] = acc;
            __syncthreads();
            for (int d = 1; d < 256; d <<= 1) {
                int u = (t >= d) ? st[t - d] : 0;
                __syncthreads();
                acc += u;
                st[t] = acc;
                __syncthreads();
            }
            int ex = acc - h;
            st[t] = ex;
            cur[t] = ex;
            __syncthreads();
            #pragma unroll
            for (int k = 0; k < 4; k++) {          // rank (1 atomic/rec)
                int j = k * 256 + t;
                if (j < cn) {
                    int p = atomicAdd(&cur[key[j]], 1);
                    inv[p] = (short)j;
                }
            }
            __syncthreads();
            for (int q = st[t]; q < cur[t]; q++) { // serial run sum, no atomics
                float4 R = stg[inv[q]];
                union HU { float f; __half2 h2; } a01, a23;
                a01.f = R.y; a23.f = R.z;
                unsigned wbits = __float_as_uint(R.w);
                float xv = R.x;
                s0 += xv;
                s1 += __low2float(a01.h2)  * xv;
                s2 += __high2float(a01.h2) * xv;
                s3 += __low2float(a23.h2)  * xv;
                s4 += __high2float(a23.h2) * xv;
                s5 += __half2float(__ushort_as_half((unsigned short)(wbits & 0xffffu))) * xv;
                dg += 1.f;
            }
            __syncthreads();
        }
        Sx[t] = s0;        Sx[256 + t] = s1;  Sx[512 + t] = s2;
        Sx[768 + t] = s3;  Sx[1024 + t] = s4; Sx[1280 + t] = s5;
        Sx[1536 + t] = dg;
        __syncthreads();
        int v0 = B << 8;
        for (int u = t; u < 256 * 12; u += 256) {
            int rel = u / 12, o = u - rel * 12;
            float dgv = Sx[1536 + rel];
            float invd = 1.f / fmaxf(dgv, 1.f);
            float msg = wsm[60 + o] * Sx[rel] + wsm[o] * Sx[256 + rel] +
                        wsm[12 + o] * Sx[512 + rel] + wsm[24 + o] * Sx[768 + rel] +
                        wsm[36 + o] * Sx[1024 + rel] + wsm[48 + o] * Sx[1280 + rel];
            float xv = A.x0[v0 + rel];
            A.y0[(size_t)(v0 + rel) * 12 + o] =
                msg * invd + xv * wsm[72 + o] + wsm[84 + o];
        }
        return;
    }
    B -= NBK0;
    int* sc = (int*)poolc;
    if (B < 1) {                                   // ---- bs1scan ----
        int c = A.bcnt1[t];
        if (c > CAP1) c = CAP1;
        sc[t] = c;
        __syncthreads();
        for (int d = 1; d < 256; d <<= 1) {
            int u = (t >= d) ? sc[t - d] : 0;
            __syncthreads();
            sc[t] += u;
            __syncthreads();
        }
        A.bs1[t] = sc[t] - c;
        if (t == 255) { A.bs1[256] = sc[255]; A.rp1[16384] = sc[255]; }
        return;
    }
    B -= 1;
    if (B < 3) {                                   // ---- scanC segs 0-2 ----
        int s = B;
        int nb = A.sg.nb[s];
        const int* cnt = A.sg.cnt[s];
        int* rp = A.sg.rp[s];
        int VPT = nb >> 8;
        int i0 = t * VPT;
        int sum = 0;
        for (int k = 0; k < VPT; k++) sum += cnt[i0 + k];
        int acc = sum;
        sc[t] = acc;
        __syncthreads();
        for (int d = 1; d < 256; d <<= 1) {
            int t2 = (t >= d) ? sc[t - d] : 0;
            __syncthreads();
            acc += t2;
            sc[t] = acc;
            __syncthreads();
        }
        int running = acc - sum;
        for (int k = 0; k < VPT; k++) {
            rp[i0 + k] = running;
            running += cnt[i0 + k];
        }
        if (t == 255) rp[nb] = running;
        return;
    }
    B -= 3;
    if (B < 1) {                                   // ---- scanC3 (cluster0) ----
        int* big = (int*)poolc;                    // 32KB
        int* scx = (int*)(poolc + 32768);          // 1KB
        int* tot = (int*)(poolc + 33792);
        const int* cnt = A.sg.cnt[3];
        int* rp = A.sg.rp[3];
        int carry = 0;
        for (int p = 0; p < 2; p++) {
            if (p == 1) carry = tot[0];
            #pragma unroll
            for (int k = 0; k < 32; k++)           // coalesced load
                big[k * 256 + t] = cnt[p * 8192 + k * 256 + t];
            __syncthreads();
            int b0 = t * 32;
            int s = 0;
            #pragma unroll
            for (int j = 0; j < 32; j++) s += big[b0 + j];
            int acc = s;
            scx[t] = acc;
            __syncthreads();
            for (int d = 1; d < 256; d <<= 1) {
                int u = (t >= d) ? scx[t - d] : 0;
                __syncthreads();
                acc += u;
                scx[t] = acc;
                __syncthreads();
            }
            if (t == 255) tot[0] = carry + acc;
            int run = carry + acc - s;
            #pragma unroll
            for (int j = 0; j < 32; j++) {
                int v = big[b0 + j];
                big[b0 + j] = run;
                run += v;
            }
            __syncthreads();
            #pragma unroll
            for (int k = 0; k < 32; k++)           // coalesced store
                rp[p * 8192 + k * 256 + t] = big[k * 256 + t];
            __syncthreads();
        }
        if (t == 255) rp[16384] = tot[0];
        return;
    }
    B -= 1;
    {                                              // ---- wstats (wave 0) ----
        if (t >= 64) return;
        int l = B;
        const float* w2l = A.w2[l];
        const float* b2l = A.b2[l];
        static const int cicoA[5] = {12, 300, 644, 1116, 1716};
        int cico = cicoA[l];
        float d[21];
        #pragma unroll
        for (int i = 0; i < 21; i++) d[i] = 0.f;
        for (int u = t; u < cico; u += 64) {
            float b = b2l[u];
            float w[5];
            #pragma unroll
            for (int k = 0; k < 5; k++) w[k] = w2l[k * cico + u];
            int p = 0;
            #pragma unroll
            for (int k = 0; k < 5; k++) {
                #pragma unroll
                for (int k2 = k; k2 < 5; k2++) d[p++] += w[k] * w[k2];
            }
            #pragma unroll
            for (int k = 0; k < 5; k++) d[15 + k] += b * w[k];
            d[20] += b * b;
        }
        #pragma unroll
        for (int i = 0; i < 21; i++) {
            #pragma unroll
            for (int off = 32; off; off >>= 1) d[i] += __shfl_down(d[i], off);
        }
        if (t == 0) {
            static const int EA[5] = {1048576, 262144, 65536, 16384, 4096};
            const float* H1 = A.H + l * 20;
            const float* H2 = H1 + 5;
            float sq = (float)EA[l] * d[20];
            #pragma unroll
            for (int k = 0; k < 5; k++) sq += 2.f * d[15 + k] * H1[k];
            int p = 0;
            #pragma unroll
            for (int k = 0; k < 5; k++) {
                #pragma unroll
                for (int k2 = k; k2 < 5; k2++) {
                    sq += ((k == k2) ? 1.f : 2.f) * d[p] * H2[p];
                    p++;
                }
            }
            A.sq[l] = sq;
        }
    }
}

// ---------------------------------------------------------------------------
// K3: scatter 4 segs (148) | bucket1 LDS-sort (256)
// ---------------------------------------------------------------------------
__global__ __launch_bounds__(256) void k3_fuseC(GA A)
{
    __shared__ float4 st4[CAP1];                   // 20KB
    __shared__ short  inv[CAP1];                   // 2.5KB
    __shared__ int h64[64], l64[64], c64[64];
    int B = blockIdx.x, t = threadIdx.x;

    if (B < A.sg.tstart[4]) {                      // ---- scatter ----
        int s = 0;
        while (s < 3 && B >= A.sg.tstart[s + 1]) s++;
        int i0 = (B - A.sg.tstart[s]) * 1024;
        const int* idx = A.sg.idx[s];
        int* cnt = A.sg.cnt[s];
        const int* rp = A.sg.rp[s];
        int* out = A.sg.out[s];
        int n = A.sg.n[s];
        #pragma unroll
        for (int j = 0; j < 4; j++) {
            int i = i0 + j * 256 + t;
            if (i < n) {
                int d = idx[i];
                int p = atomicSub(&cnt[d], 1) - 1;
                out[rp[d] + p] = i;
            }
        }
        return;
    }
    B -= A.sg.tstart[4];
    {                                              // ---- bucket1 ----
        int b = B;
        int n = A.bcnt1[b];
        if (n > CAP1) n = CAP1;
        size_t base = (size_t)b * CAP1;
        for (int j = t; j < n; j += 256) st4[j] = A.pay1[base + j];
        if (t < 64) h64[t] = 0;
        __syncthreads();
        for (int j = t; j < n; j += 256) {
            int rel = (int)(__float_as_uint(st4[j].x) >> 16) & 63;
            atomicAdd(&h64[rel], 1);
        }
        __syncthreads();
        if (t < 64) {                              // wave-level exclusive scan
            int v = h64[t];
            int val = v;
            #pragma unroll
            for (int d = 1; d < 64; d <<= 1) {
                int u = __shfl_up(val, d);
                if (t >= d) val += u;
            }
            l64[t] = val - v;
            c64[t] = val - v;
        }
        __syncthreads();
        for (int j = t; j < n; j += 256) {
            int rel = (int)(__float_as_uint(st4[j].x) >> 16) & 63;
            int p = atomicAdd(&c64[rel], 1);
            inv[p] = (short)j;
        }
        __syncthreads();
        int lo = A.bs1[b];
        for (int j = t; j < n; j += 256)           // coalesced sorted write
            A.rec1[lo + j] = st4[inv[j]];
        if (t < 64) A.rp1[(b << 6) + t] = lo + l64[t];
    }
}

// ---------------------------------------------------------------------------
// K4: pool0 (960)
// ---------------------------------------------------------------------------
__global__ __launch_bounds__(256) void k4_pool0(GA A)
{
    int gt = blockIdx.x * 256 + threadIdx.x;
    if (gt >= 16384 * 15) return;
    int c = gt / 15, o = gt - c * 15;
    int r0 = A.sg.rp[3][c], r1 = A.sg.rp[3][c + 1];
    const int* cnid = A.sg.out[3];
    int d = r1 - r0;
    if (o < 12) {
        float m = -INFINITY;
        for (int j = r0; j < r1; j++)
            m = fmaxf(m, A.y0[(size_t)cnid[j] * 12 + o]);
        if (d == 0 || !isfinite(m)) m = 0.f;
        A.xn0[c * 15 + o] = m;
    } else {
        int k = o - 12;
        float sum = 0.f;
        for (int j = r0; j < r1; j++)
            sum += A.pos0[cnid[j] * 3 + k];
        A.xn0[c * 15 + o] = sum / fmaxf((float)d, 1.f);
    }
}

// ---------------------------------------------------------------------------
// K5: conv1 (block/node, streams rec1, plain xn0 input) + pool->raw1
// ---------------------------------------------------------------------------
__global__ __launch_bounds__(256) void k5_conv1(GA A)
{
    constexpr int CI = 15, CO = 20, CH = 48, CICO = CI * CO, RN = 24;
    __shared__ float w1s[20];
    __shared__ float4 recb[CH];
    __shared__ int   svb[CH];
    __shared__ float hb[CH * 6];
    __shared__ float xs[CH * CI];
    __shared__ float Sx[6 * CI];
    __shared__ float xown[CI];

    int t = threadIdx.x, v = blockIdx.x;
    if (t < 20) w1s[t] = (t < 15) ? A.w1[1][t] : A.b1[1][t - 15];
    if (t < CI) xown[t] = A.xn0[v * CI + t];
    int r0 = A.rp1[v], r1 = A.rp1[v + 1];
    int d = r1 - r0;
    float acc = 0.f;

    for (int c0 = r0; c0 < r1; c0 += CH) {
        int cn = min(CH, r1 - c0);
        if (t < cn) {
            float4 R = A.rec1[c0 + t];
            recb[t] = R;
            svb[t]  = (int)(__float_as_uint(R.x) & 0xffffu);
            hb[t * 6] = 1.f;
        }
        __syncthreads();
        if (t < cn * 5) {
            int j = t / 5, k = t % 5;
            float e0 = recb[j].y, e1 = recb[j].z, e2 = recb[j].w;
            hb[j * 6 + 1 + k] =
                ftanh(e0 * w1s[k] + e1 * w1s[5 + k] + e2 * w1s[10 + k] + w1s[15 + k]);
        }
        for (int u = t; u < cn * CI; u += 256) {
            int j = u / CI, i = u - j * CI;
            xs[u] = A.xn0[svb[j] * CI + i];
        }
        __syncthreads();
        if (t < 6 * CI) {
            int i = t / 6, k6 = t - (t / 6) * 6;
            for (int j = 0; j < cn; j++)
                acc += hb[j * 6 + k6] * xs[j * CI + i];
        }
        __syncthreads();
    }

    if (t < 6 * CI) Sx[t] = acc;
    __syncthreads();

    if (t < CO) {
        float m = 0.f;
        const float* w2 = A.w2[1];
        const float* b2 = A.b2[1];
        for (int i = 0; i < CI; i++) {
            m += b2[i * CO + t] * Sx[i * 6];
            #pragma unroll
            for (int k = 0; k < 5; k++)
                m += w2[k * CICO + i * CO + t] * Sx[i * 6 + 1 + k];
        }
        m /= fmaxf((float)d, 1.f);
        for (int i = 0; i < CI; i++) m += xown[i] * A.root[1][i * CO + t];
        m += A.bias[1][t];
        int c = A.cluster[1][v];
        unsigned* orow = A.raw[1] + (size_t)c * RN;
        atomicMax(&orow[t], fenc(m));
        if (t < 3) atomicAdd((float*)&orow[CO + t], xown[CI - 3 + t]);
        if (t == 0) atomicAdd((float*)&orow[CO + 3], 1.f);
    }
}

// ---------------------------------------------------------------------------
// K6-8: coop conv levels 2-4 + fused pool epilogue
// ---------------------------------------------------------------------------
template<int CI, int CO>
__global__ __launch_bounds__(256) void coopP_k(GA A, int l)
{
    constexpr int CH = 48, CICO = CI * CO, RL = CI + 1, RN = CO + 4;
    __shared__ float w1s[20];
    __shared__ int   eb[CH], svb[CH];
    __shared__ float hb[CH * 6];
    __shared__ float xs[CH * CI];
    __shared__ float Sx[6 * CI];
    __shared__ float xown[CI];

    int t = threadIdx.x, v = blockIdx.x;
    int s = l - 2;
    const unsigned* rin = A.raw[l - 1];
    const int* rp = A.sg.rp[s];
    const int* eid = A.sg.out[s];
    const int* src = A.srcE[s];
    const float* eattr = A.eaE[s];

    if (t < 20) w1s[t] = (t < 15) ? A.w1[l][t] : A.b1[l][t - 15];
    if (t < CI) xown[t] = row_val(rin + (size_t)v * RL, t, CI);
    int r0 = rp[v], r1 = rp[v + 1];
    int d = r1 - r0;
    float acc = 0.f;

    for (int c0 = r0; c0 < r1; c0 += CH) {
        int cn = min(CH, r1 - c0);
        if (t < cn) {
            int e = eid[c0 + t];
            eb[t]  = e;
            svb[t] = src[e];
            hb[t * 6] = 1.f;
        }
        __syncthreads();
        if (t < cn * 5) {
            int j = t / 5, k = t % 5;
            int e = eb[j];
            float e0 = eattr[e * 3], e1 = eattr[e * 3 + 1], e2 = eattr[e * 3 + 2];
            hb[j * 6 + 1 + k] =
                ftanh(e0 * w1s[k] + e1 * w1s[5 + k] + e2 * w1s[10 + k] + w1s[15 + k]);
        }
        for (int u = t; u < cn * CI; u += 256) {
            int j = u / CI, i = u - j * CI;
            xs[u] = row_val(rin + (size_t)svb[j] * RL, i, CI);
        }
        __syncthreads();
        if (t < 6 * CI) {
            int i = t / 6, k6 = t - (t / 6) * 6;
            for (int j = 0; j < cn; j++)
                acc += hb[j * 6 + k6] * xs[j * CI + i];
        }
        __syncthreads();
    }

    if (t < 6 * CI) Sx[t] = acc;
    __syncthreads();

    if (t < CO) {
        float m = 0.f;
        const float* w2 = A.w2[l];
        const float* b2 = A.b2[l];
        for (int i = 0; i < CI; i++) {
            m += b2[i * CO + t] * Sx[i * 6];
            #pragma unroll
            for (int k = 0; k < 5; k++)
                m += w2[k * CICO + i * CO + t] * Sx[i * 6 + 1 + k];
        }
        m /= fmaxf((float)d, 1.f);
        for (int i = 0; i < CI; i++) m += xown[i] * A.root[l][i * CO + t];
        m += A.bias[l][t];
        int c = A.cluster[l][v];
        unsigned* orow = A.raw[l] + (size_t)c * RN;
        atomicMax(&orow[t], fenc(m));
        if (t < 3) atomicAdd((float*)&orow[CO + t], xown[CI - 3 + t]);
        if (t == 0) atomicAdd((float*)&orow[CO + 3], 1.f);
    }
}

// ---------------------------------------------------------------------------
// K9: fc (decodes raw[4])
// ---------------------------------------------------------------------------
__global__ __launch_bounds__(128) void k9_fc(GA A)
{
    __shared__ float feat[8 * 376];
    __shared__ float logit[80];
    __shared__ float roff[8];
    const unsigned* r5 = A.raw[4];
    for (int idx = threadIdx.x; idx < 64 * 47; idx += 128) {
        int n = idx / 47, i = idx - n * 47;
        int b = n >> 3, s = n & 7;
        feat[b * 376 + s * 47 + i] = row_val(r5 + (size_t)n * 48, i, 47);
    }
    __syncthreads();
    int t = threadIdx.x;
    if (t < 80) {
        int b = t / 10, j = t % 10;
        float acc = A.fc_b[j];
        for (int k = 0; k < 376; k++) acc += feat[b * 376 + k] * A.fc_w[k * 10 + j];
        logit[t] = acc;
    }
    __syncthreads();
    if (t < 8) {
        float m = -1e30f;
        for (int j = 0; j < 10; j++) m = fmaxf(m, logit[t * 10 + j]);
        float ssum = 0.f;
        for (int j = 0; j < 10; j++) ssum += expf(logit[t * 10 + j] - m);
        roff[t] = m + logf(ssum);
    }
    __syncthreads();
    if (t < 80) A.out[t] = logit[t] - roff[t / 10];
    if (t == 0) {
        const float* sq = A.sq;
        float closs = 0.f;
        closs += sq[0] * (1.0f / 12582912.0f);
        closs += sq[1] * (1.0f / 78643200.0f);
        closs += sq[2] * (1.0f / 42205184.0f);
        closs += sq[3] * (1.0f / 18284544.0f);
        closs += sq[4] * (1.0f / 7028736.0f);
        A.out[80] = closs;
    }
}

// ---------------------------------------------------------------------------

extern "C" void kernel_launch(void* const* d_in, const int* in_sizes, int n_in,
                              void* d_out, int out_size, void* d_ws, size_t ws_size,
                              hipStream_t stream)
{
    static const int NSa[6] = {65536, 16384, 4096, 1024, 256, 64};
    static const int ESa[5] = {1048576, 262144, 65536, 16384, 4096};
    static const int RNa[5] = {16, 24, 32, 40, 48};   // raw row widths (words)

    // ---- workspace layout (words) ----
    int* wsw = (int*)d_ws;
    size_t off = 0;
    auto alw = [&](size_t n) -> size_t {
        size_t p = off; off += (n + 63) & ~(size_t)63; return p;
    };
    // zeroed region
    size_t degO[5];
    for (int l = 2; l < 5; l++) degO[l] = alw(NSa[l]);
    size_t cdeg0O = alw(NSa[1]);                      // cluster0 counts
    size_t HO    = alw(100);
    size_t bcO   = alw(NBK0);
    size_t bc1O  = alw(NBK1);
    size_t rawO[5];
    for (int l = 1; l < 5; l++) rawO[l] = alw((size_t)NSa[l + 1] * RNa[l]);
    size_t zeroWords = off;
    // non-zeroed
    size_t rpO[5], eidO[5];
    for (int l = 2; l < 5; l++) rpO[l]  = alw(NSa[l] + 1);
    size_t crp0O = alw(NSa[1] + 1);
    for (int l = 2; l < 5; l++) eidO[l] = alw(ESa[l]);
    size_t cnid0O = alw(NSa[0]);
    size_t pay2O = alw((size_t)NBK0 * CAP0 * 4);
    size_t y0O   = alw((size_t)NSa[0] * 12);
    size_t xn0O  = alw((size_t)NSa[1] * 15);
    size_t bs1O  = alw(NBK1 + 1);
    size_t pay1O = alw((size_t)NBK1 * CAP1 * 4);
    size_t rec1O = alw((size_t)ESa[1] * 4);
    size_t rp1O  = alw(NSa[1] + 1);
    size_t sqO   = alw(8);

    GA A{};
    A.src0 = (const int*)d_in[2];  A.dst0 = (const int*)d_in[3];
    A.ea0  = (const float*)d_in[4];
    A.src1 = (const int*)d_in[12]; A.dst1 = (const int*)d_in[13];
    A.ea1  = (const float*)d_in[14];
    A.x0   = (const float*)d_in[0];
    A.pos0 = (const float*)d_in[1];
    for (int l = 0; l < 5; l++) {
        A.cluster[l] = (const int*)d_in[5 + 10 * l];
        A.w1[l]   = (const float*)d_in[6 + 10 * l];
        A.b1[l]   = (const float*)d_in[7 + 10 * l];
        A.w2[l]   = (const float*)d_in[8 + 10 * l];
        A.b2[l]   = (const float*)d_in[9 + 10 * l];
        A.root[l] = (const float*)d_in[10 + 10 * l];
        A.bias[l] = (const float*)d_in[11 + 10 * l];
    }
    for (int s = 0; s < 3; s++) {
        A.srcE[s] = (const int*)d_in[2 + 10 * (s + 2)];
        A.eaE[s]  = (const float*)d_in[4 + 10 * (s + 2)];
    }
    A.fc_w = (const float*)d_in[52];
    A.fc_b = (const float*)d_in[53];
    A.bcnt  = wsw + bcO;
    A.bcnt1 = wsw + bc1O;
    A.pay2 = (float4*)(wsw + pay2O);
    A.pay1 = (float4*)(wsw + pay1O);
    A.rec1 = (float4*)(wsw + rec1O);
    A.y0   = (float*)(wsw + y0O);
    A.xn0  = (float*)(wsw + xn0O);
    for (int l = 1; l < 5; l++) A.raw[l] = (unsigned*)(wsw + rawO[l]);
    A.H  = (float*)(wsw + HO);
    A.sq = (float*)(wsw + sqO);
    A.bs1 = wsw + bs1O;
    A.rp1 = wsw + rp1O;
    A.out = (float*)d_out;

    // seg descriptors: 0-2 = edge segs L2-4, 3 = cluster0
    int tiles = 0;
    for (int s = 0; s < 3; s++) {
        int l = s + 2;
        A.sg.idx[s] = (const int*)d_in[3 + 10 * l];
        A.sg.cnt[s] = wsw + degO[l];
        A.sg.rp [s] = wsw + rpO[l];
        A.sg.out[s] = wsw + eidO[l];
        A.sg.n  [s] = ESa[l];
        A.sg.nb [s] = NSa[l];
        A.sg.tstart[s] = tiles;
        tiles += (ESa[l] + 1023) / 1024;
    }
    A.sg.idx[3] = (const int*)d_in[5];              // cluster0
    A.sg.cnt[3] = wsw + cdeg0O;
    A.sg.rp [3] = wsw + crp0O;
    A.sg.out[3] = wsw + cnid0O;
    A.sg.n  [3] = NSa[0];
    A.sg.nb [3] = NSa[1];
    A.sg.tstart[3] = tiles;
    tiles += (NSa[0] + 1023) / 1024;
    A.sg.tstart[4] = tiles;                          // 148

    int hsB = 0;
    A.hb0[0] = 0;
    for (int j = 0; j < 3; j++) {                    // hstats: levels 2-4
        hsB += (ESa[j + 2] + 2047) / 2048;
        A.hb0[j + 1] = hsB;
    }
    A.hsB = hsB;                                     // 42

    hipMemsetAsync(d_ws, 0, zeroWords * 4, stream);

    k1_fuseA<<<NT0 + NT1 + hsB + tiles, 256, 0, stream>>>(A);   // 1470
    k2_fuseB<<<NBK0 + 1 + 3 + 1 + 5,    256, 0, stream>>>(A);   // 266
    k3_fuseC<<<tiles + NBK1,            256, 0, stream>>>(A);   // 404
    k4_pool0<<<(16384 * 15 + 255) / 256, 256, 0, stream>>>(A);  // 960
    k5_conv1<<<NSa[1],                  256, 0, stream>>>(A);   // 16384
    coopP_k<23, 28><<<NSa[2],           256, 0, stream>>>(A, 2);
    coopP_k<31, 36><<<NSa[3],           256, 0, stream>>>(A, 3);
    coopP_k<39, 44><<<NSa[4],           256, 0, stream>>>(A, 4);
    k9_fc<<<1, 128, 0, stream>>>(A);
}

// Round 11
// 345.342 us; speedup vs baseline: 1.0311x; 1.0311x over previous
//
#include <hip/hip_runtime.h>
#include <hip/hip_fp16.h>
#include <math.h>

// ---------------------------------------------------------------------------
// Net_37512244363273: 5-level edge-conditioned graph conv + voxel pooling + FC
// Round 26: restore R22 exactly (best measured: 338.9us). A/B ledger:
//  R22 338.9 | R23 360.4 (perm-pool0 +12, wave-convs +9.5) | R24 350.9
//  (perm-pool0 only) | R25 356.1 (k1 1024-tiles: +9 on k1, frag'd pay2).
// k1 @ R22 config: VALU 11%, HBM 12%, occ 22%, no saturated pipe --
// balanced tanh/LDS-sort/HBM mix; both tile-size directions measured worse.
// All other dispatches < 42us harness fill. Converged.
// Pipeline: memset | k1 part0+part1+hstats+hist | k2 conv0c+bs1scan+scanC+
// scanC3+wstats | k3 scatter+bucket1 | k4 pool0 | k5 conv1 | k6-8 conv2-4 |
// k9 fc.
// ---------------------------------------------------------------------------

#define NT0   512                  // part0 tiles (2048 edges)
#define TSZ0  2048
#define NBK0  256                  // L0 buckets (dst>>8, 256 nodes each)
#define CAP0  4608                 // per-bucket capacity (avg 4096 + 8 sigma)
#define NT1   128                  // part1 tiles (2048 edges)
#define TSZ1  2048
#define NBK1  256                  // L1 buckets (dst>>6, 64 nodes each)
#define CAP1  1280                 // per-bucket capacity (avg 1024 + 8 sigma)

__device__ __forceinline__ float ftanh(float x) {
    float e = __expf(2.f * x);
    return 1.f - 2.f / (e + 1.f);
}

// order-preserving float<->uint (monotone): enables atomicMax-based fmax
__device__ __forceinline__ unsigned fenc(float f) {
    int b = __float_as_int(f);
    return (b < 0) ? ~(unsigned)b : ((unsigned)b | 0x80000000u);
}
__device__ __forceinline__ float fdec(unsigned u) {
    int b = (u & 0x80000000u) ? (int)(u & 0x7fffffffu) : ~(int)u;
    return __int_as_float(b);
}

// decode element i of a pooled raw row [CI-3 max-enc | 3 possum | 1 cnt]
__device__ __forceinline__ float row_val(const unsigned* __restrict__ row,
                                         int i, int CI) {
    float cn = __uint_as_float(row[CI]);
    if (i < CI - 3) return (cn == 0.f) ? 0.f : fdec(row[i]);
    return __uint_as_float(row[i]) / fmaxf(cn, 1.f);
}

struct Seg4 {                       // edge segs L2-4 + cluster0 seg
    const int* idx[4];
    int*       cnt[4];
    int*       rp [4];
    int*       out[4];
    int        n  [4];
    int        nb [4];
    int        tstart[5];
};

struct GA {
    // inputs
    const int *src0, *dst0; const float* ea0;
    const int *src1, *dst1; const float* ea1;
    const float *x0, *pos0;
    const int* cluster[5];
    const float *w1[5], *b1[5], *w2[5], *b2[5], *root[5], *bias[5];
    const int* srcE[3]; const float* eaE[3];
    const float *fc_w, *fc_b;
    // workspace
    int *bcnt, *bcnt1;              // [NBK0]/[NBK1] reservation counters
    float4 *pay2, *pay1, *rec1;
    float *y0, *xn0;
    unsigned* raw[5];               // pooled rows for levels 1-4
    float *H, *sq;
    int *bs1, *rp1;
    Seg4 sg;
    float* out;
    int hb0[4], hsB;                // hstats (levels 2-4 only)
};

// ---------------------------------------------------------------------------
// K1: part0 (512) | part1 (128) | hstats L2-4 (42) | hist 4 segs (148)
// Shared LDS (union across roles): 32KB staging + 2KB bucket-tags + 4KB scans
// ---------------------------------------------------------------------------
__global__ __launch_bounds__(256) void k1_fuseA(GA A)
{
    __shared__ float4 stg[TSZ0];                   // 32KB
    __shared__ unsigned char bkb[TSZ0];            // 2KB
    __shared__ int hb_[256], gb_[256], ls_[256], cu_[256];

    int B = blockIdx.x, t = threadIdx.x;

    if (B < NT0) {                                 // ---- part0-append ----
        hb_[t] = 0;
        __syncthreads();
        int base = B * TSZ0 + t;
        int dreg[8];
        #pragma unroll
        for (int k = 0; k < 8; k++) {
            dreg[k] = A.dst0[base + k * 256];
            atomicAdd(&hb_[dreg[k] >> 8], 1);
        }
        __syncthreads();
        int c = hb_[t];
        gb_[t] = c ? atomicAdd(&A.bcnt[t], c) : 0;
        ls_[t] = c;
        __syncthreads();
        for (int d = 1; d < 256; d <<= 1) {
            int u = (t >= d) ? ls_[t - d] : 0;
            __syncthreads();
            ls_[t] += u;
            __syncthreads();
        }
        int ex = ls_[t] - c;
        ls_[t] = ex;
        cu_[t] = ex;
        __syncthreads();

        float w1r[15], b1r[5];
        #pragma unroll
        for (int i = 0; i < 15; i++) w1r[i] = A.w1[0][i];
        #pragma unroll
        for (int i = 0; i < 5; i++)  b1r[i] = A.b1[0][i];
        float acc[20];
        #pragma unroll
        for (int i = 0; i < 20; i++) acc[i] = 0.f;
        #pragma unroll
        for (int k = 0; k < 8; k++) {
            int i = base + k * 256;
            int d = dreg[k];
            int sv = A.src0[i];
            float e0 = A.ea0[i * 3], e1 = A.ea0[i * 3 + 1], e2 = A.ea0[i * 3 + 2];
            float h[5];
            #pragma unroll
            for (int q = 0; q < 5; q++)
                h[q] = ftanh(e0 * w1r[q] + e1 * w1r[5 + q] + e2 * w1r[10 + q] + b1r[q]);
            int p = 5;
            #pragma unroll
            for (int q = 0; q < 5; q++) {
                acc[q] += h[q];
                #pragma unroll
                for (int q2 = q; q2 < 5; q2++) acc[p++] += h[q] * h[q2];
            }
            float xv = A.x0[sv];
            union HU { __half2 h2; float f; } p01, p23;
            p01.h2 = __floats2half2_rn(h[0], h[1]);
            p23.h2 = __floats2half2_rn(h[2], h[3]);
            unsigned wbits = ((unsigned)d << 16) |
                             (unsigned)__half_as_ushort(__float2half_rn(h[4]));
            int bk = d >> 8;
            int ps = atomicAdd(&cu_[bk], 1);
            stg[ps] = make_float4(xv, p01.f, p23.f, __uint_as_float(wbits));
            bkb[ps] = (unsigned char)bk;
        }
        __syncthreads();
        #pragma unroll
        for (int k = 0; k < 8; k++) {              // coalesced-run write-out
            int p = k * 256 + t;
            int bk = bkb[p];
            int off = gb_[bk] + (p - ls_[bk]);
            if (off < CAP0)
                A.pay2[(size_t)bk * CAP0 + off] = stg[p];
        }
        __syncthreads();
        float* red = (float*)cu_;
        int wid = t >> 6, lane = t & 63;
        #pragma unroll
        for (int v = 0; v < 20; v++) {
            float s = acc[v];
            #pragma unroll
            for (int o = 32; o; o >>= 1) s += __shfl_down(s, o);
            if (lane == 0) red[wid * 20 + v] = s;
        }
        __syncthreads();
        if (t < 20)
            atomicAdd(&A.H[t], red[t] + red[20 + t] + red[40 + t] + red[60 + t]);
        return;
    }
    B -= NT0;
    if (B < NT1) {                                 // ---- part1-append ----
        hb_[t] = 0;
        __syncthreads();
        int base = B * TSZ1 + t;
        int dreg[8];
        #pragma unroll
        for (int k = 0; k < 8; k++) {
            dreg[k] = A.dst1[base + k * 256];
            atomicAdd(&hb_[dreg[k] >> 6], 1);
        }
        __syncthreads();
        int c = hb_[t];
        gb_[t] = c ? atomicAdd(&A.bcnt1[t], c) : 0;
        ls_[t] = c;
        __syncthreads();
        for (int d = 1; d < 256; d <<= 1) {
            int u = (t >= d) ? ls_[t - d] : 0;
            __syncthreads();
            ls_[t] += u;
            __syncthreads();
        }
        int ex = ls_[t] - c;
        ls_[t] = ex;
        cu_[t] = ex;
        __syncthreads();

        float w1r[15], b1r[5];
        #pragma unroll
        for (int i = 0; i < 15; i++) w1r[i] = A.w1[1][i];
        #pragma unroll
        for (int i = 0; i < 5; i++)  b1r[i] = A.b1[1][i];
        float acc[20];
        #pragma unroll
        for (int i = 0; i < 20; i++) acc[i] = 0.f;
        #pragma unroll
        for (int k = 0; k < 8; k++) {
            int i = base + k * 256;
            int d = dreg[k];
            int sv = A.src1[i];
            float e0 = A.ea1[i * 3], e1 = A.ea1[i * 3 + 1], e2 = A.ea1[i * 3 + 2];
            float h[5];
            #pragma unroll
            for (int q = 0; q < 5; q++)
                h[q] = ftanh(e0 * w1r[q] + e1 * w1r[5 + q] + e2 * w1r[10 + q] + b1r[q]);
            int p = 5;
            #pragma unroll
            for (int q = 0; q < 5; q++) {
                acc[q] += h[q];
                #pragma unroll
                for (int q2 = q; q2 < 5; q2++) acc[p++] += h[q] * h[q2];
            }
            int bk = d >> 6;
            int ps = atomicAdd(&cu_[bk], 1);
            stg[ps] = make_float4(__int_as_float((d << 16) | sv), e0, e1, e2);
            bkb[ps] = (unsigned char)bk;
        }
        __syncthreads();
        #pragma unroll
        for (int k = 0; k < 8; k++) {
            int p = k * 256 + t;
            int bk = bkb[p];
            int off = gb_[bk] + (p - ls_[bk]);
            if (off < CAP1)
                A.pay1[(size_t)bk * CAP1 + off] = stg[p];
        }
        __syncthreads();
        float* red = (float*)cu_;
        int wid = t >> 6, lane = t & 63;
        #pragma unroll
        for (int v = 0; v < 20; v++) {
            float s = acc[v];
            #pragma unroll
            for (int o = 32; o; o >>= 1) s += __shfl_down(s, o);
            if (lane == 0) red[wid * 20 + v] = s;
        }
        __syncthreads();
        if (t < 20)
            atomicAdd(&A.H[20 + t], red[t] + red[20 + t] + red[40 + t] + red[60 + t]);
        return;
    }
    B -= NT1;
    if (B < A.hsB) {                               // ---- hstats (L2-4) ----
        const int K = 8;
        int j = 0;
        while (j < 2 && B >= A.hb0[j + 1]) j++;
        int bloc = B - A.hb0[j];
        const float* ea = A.eaE[j];
        const float* w1p = A.w1[j + 2];
        const float* b1p = A.b1[j + 2];
        static const int EJ[3] = {65536, 16384, 4096};
        int Ej = EJ[j];
        float w1r[15], b1r[5];
        #pragma unroll
        for (int i = 0; i < 15; i++) w1r[i] = w1p[i];
        #pragma unroll
        for (int i = 0; i < 5; i++)  b1r[i] = b1p[i];
        float acc[20];
        #pragma unroll
        for (int i = 0; i < 20; i++) acc[i] = 0.f;
        int base = bloc * 256 * K + t;
        for (int it = 0; it < K; it++) {
            int e = base + it * 256;
            if (e < Ej) {
                float e0 = ea[e * 3], e1 = ea[e * 3 + 1], e2 = ea[e * 3 + 2];
                float h[5];
                #pragma unroll
                for (int q = 0; q < 5; q++)
                    h[q] = ftanh(e0 * w1r[q] + e1 * w1r[5 + q] + e2 * w1r[10 + q] + b1r[q]);
                int p = 5;
                #pragma unroll
                for (int q = 0; q < 5; q++) {
                    acc[q] += h[q];
                    #pragma unroll
                    for (int q2 = q; q2 < 5; q2++) acc[p++] += h[q] * h[q2];
                }
            }
        }
        float* red = (float*)hb_;
        int wid = t >> 6, lane = t & 63;
        #pragma unroll
        for (int v = 0; v < 20; v++) {
            float s = acc[v];
            #pragma unroll
            for (int o = 32; o; o >>= 1) s += __shfl_down(s, o);
            if (lane == 0) red[wid * 20 + v] = s;
        }
        __syncthreads();
        if (t < 20)
            atomicAdd(&A.H[(j + 2) * 20 + t],
                      red[t] + red[20 + t] + red[40 + t] + red[60 + t]);
        return;
    }
    B -= A.hsB;
    {                                              // ---- hist (4 segs) ----
        int s = 0;
        while (s < 3 && B >= A.sg.tstart[s + 1]) s++;
        int i0 = (B - A.sg.tstart[s]) * 1024;
        const int* idx = A.sg.idx[s];
        int* cnt = A.sg.cnt[s];
        int n = A.sg.n[s];
        #pragma unroll
        for (int j = 0; j < 4; j++) {
            int i = i0 + j * 256 + t;
            if (i < n) atomicAdd(&cnt[idx[i]], 1);
        }
    }
}

// ---------------------------------------------------------------------------
// K2: conv0c v2 (256) | bs1scan (1) | scanC segs 0-2 (3) | scanC3 (1) |
//     wstats (5).  LDS pool 34KB (union across roles).
// ---------------------------------------------------------------------------
__global__ __launch_bounds__(256) void k2_fuseB(GA A)
{
    __shared__ alignas(16) char poolc[34048];
    int B = blockIdx.x, t = threadIdx.x;

    if (B < NBK0) {                                // ---- conv0c v2 ----
        float4* stg = (float4*)poolc;                          // 16KB
        float*  Sx  = (float*)(poolc + 16384);                 // 7KB
        unsigned char* key = (unsigned char*)(poolc + 23552);  // 1KB
        short* inv = (short*)(poolc + 24576);                  // 2KB
        int* hist = (int*)(poolc + 26624);
        int* st   = (int*)(poolc + 27648);
        int* cur  = (int*)(poolc + 28672);
        float* wsm = (float*)(poolc + 29696);                  // 96 floats

        if (t < 60) wsm[t] = A.w2[0][t];
        else if (t >= 64  && t < 76)  wsm[60 + t - 64]  = A.b2[0][t - 64];
        else if (t >= 128 && t < 140) wsm[72 + t - 128] = A.root[0][t - 128];
        else if (t >= 192 && t < 204) wsm[84 + t - 192] = A.bias[0][t - 192];

        int n = A.bcnt[B];
        if (n > CAP0) n = CAP0;
        size_t base = (size_t)B * CAP0;
        float s0 = 0.f, s1 = 0.f, s2 = 0.f, s3 = 0.f, s4 = 0.f, s5 = 0.f, dg = 0.f;

        for (int c0 = 0; c0 < n; c0 += 1024) {
            int cn = min(1024, n - c0);
            hist[t] = 0;
            __syncthreads();
            #pragma unroll
            for (int k = 0; k < 4; k++) {          // load + hist (1 atomic/rec)
                int j = k * 256 + t;
                if (j < cn) {
                    float4 R = A.pay2[base + c0 + j];
                    stg[j] = R;
                    int rel = (int)(__float_as_uint(R.w) >> 16) & 255;
                    key[j] = (unsigned char)rel;
                    atomicAdd(&hist[rel], 1);
                }
            }
            __syncthreads();
            int h = hist[t];                       // block scan
            int acc = h;
            st[t] = acc;
            __syncthreads();
            for (int d = 1; d < 256; d <<= 1) {
                int u = (t >= d) ? st[t - d] : 0;
                __syncthreads();
                acc += u;
                st[t] = acc;
                __syncthreads();
            }
            int ex = acc - h;
            st[t] = ex;
            cur[t] = ex;
            __syncthreads();
            #pragma unroll
            for (int k = 0; k < 4; k++) {          // rank (1 atomic/rec)
                int j = k * 256 + t;
                if (j < cn) {
                    int p = atomicAdd(&cur[key[j]], 1);
                    inv[p] = (short)j;
                }
            }
            __syncthreads();
            for (int q = st[t]; q < cur[t]; q++) { // serial run sum, no atomics
                float4 R = stg[inv[q]];
                union HU { float f; __half2 h2; } a01, a23;
                a01.f = R.y; a23.f = R.z;
                unsigned wbits = __float_as_uint(R.w);
                float xv = R.x;
                s0 += xv;
                s1 += __low2float(a01.h2)  * xv;
                s2 += __high2float(a01.h2) * xv;
                s3 += __low2float(a23.h2)  * xv;
                s4 += __high2float(a23.h2) * xv;
                s5 += __half2float(__ushort_as_half((unsigned short)(wbits & 0xffffu))) * xv;
                dg += 1.f;
            }
            __syncthreads();
        }
        Sx[t] = s0;        Sx[256 + t] = s1;  Sx[512 + t] = s2;
        Sx[768 + t] = s3;  Sx[1024 + t] = s4; Sx[1280 + t] = s5;
        Sx[1536 + t] = dg;
        __syncthreads();
        int v0 = B << 8;
        for (int u = t; u < 256 * 12; u += 256) {
            int rel = u / 12, o = u - rel * 12;
            float dgv = Sx[1536 + rel];
            float invd = 1.f / fmaxf(dgv, 1.f);
            float msg = wsm[60 + o] * Sx[rel] + wsm[o] * Sx[256 + rel] +
                        wsm[12 + o] * Sx[512 + rel] + wsm[24 + o] * Sx[768 + rel] +
                        wsm[36 + o] * Sx[1024 + rel] + wsm[48 + o] * Sx[1280 + rel];
            float xv = A.x0[v0 + rel];
            A.y0[(size_t)(v0 + rel) * 12 + o] =
                msg * invd + xv * wsm[72 + o] + wsm[84 + o];
        }
        return;
    }
    B -= NBK0;
    int* sc = (int*)poolc;
    if (B < 1) {                                   // ---- bs1scan ----
        int c = A.bcnt1[t];
        if (c > CAP1) c = CAP1;
        sc[t] = c;
        __syncthreads();
        for (int d = 1; d < 256; d <<= 1) {
            int u = (t >= d) ? sc[t - d] : 0;
            __syncthreads();
            sc[t] += u;
            __syncthreads();
        }
        A.bs1[t] = sc[t] - c;
        if (t == 255) { A.bs1[256] = sc[255]; A.rp1[16384] = sc[255]; }
        return;
    }
    B -= 1;
    if (B < 3) {                                   // ---- scanC segs 0-2 ----
        int s = B;
        int nb = A.sg.nb[s];
        const int* cnt = A.sg.cnt[s];
        int* rp = A.sg.rp[s];
        int VPT = nb >> 8;
        int i0 = t * VPT;
        int sum = 0;
        for (int k = 0; k < VPT; k++) sum += cnt[i0 + k];
        int acc = sum;
        sc[t] = acc;
        __syncthreads();
        for (int d = 1; d < 256; d <<= 1) {
            int t2 = (t >= d) ? sc[t - d] : 0;
            __syncthreads();
            acc += t2;
            sc[t] = acc;
            __syncthreads();
        }
        int running = acc - sum;
        for (int k = 0; k < VPT; k++) {
            rp[i0 + k] = running;
            running += cnt[i0 + k];
        }
        if (t == 255) rp[nb] = running;
        return;
    }
    B -= 3;
    if (B < 1) {                                   // ---- scanC3 (cluster0) ----
        int* big = (int*)poolc;                    // 32KB
        int* scx = (int*)(poolc + 32768);          // 1KB
        int* tot = (int*)(poolc + 33792);
        const int* cnt = A.sg.cnt[3];
        int* rp = A.sg.rp[3];
        int carry = 0;
        for (int p = 0; p < 2; p++) {
            if (p == 1) carry = tot[0];
            #pragma unroll
            for (int k = 0; k < 32; k++)           // coalesced load
                big[k * 256 + t] = cnt[p * 8192 + k * 256 + t];
            __syncthreads();
            int b0 = t * 32;
            int s = 0;
            #pragma unroll
            for (int j = 0; j < 32; j++) s += big[b0 + j];
            int acc = s;
            scx[t] = acc;
            __syncthreads();
            for (int d = 1; d < 256; d <<= 1) {
                int u = (t >= d) ? scx[t - d] : 0;
                __syncthreads();
                acc += u;
                scx[t] = acc;
                __syncthreads();
            }
            if (t == 255) tot[0] = carry + acc;
            int run = carry + acc - s;
            #pragma unroll
            for (int j = 0; j < 32; j++) {
                int v = big[b0 + j];
                big[b0 + j] = run;
                run += v;
            }
            __syncthreads();
            #pragma unroll
            for (int k = 0; k < 32; k++)           // coalesced store
                rp[p * 8192 + k * 256 + t] = big[k * 256 + t];
            __syncthreads();
        }
        if (t == 255) rp[16384] = tot[0];
        return;
    }
    B -= 1;
    {                                              // ---- wstats (wave 0) ----
        if (t >= 64) return;
        int l = B;
        const float* w2l = A.w2[l];
        const float* b2l = A.b2[l];
        static const int cicoA[5] = {12, 300, 644, 1116, 1716};
        int cico = cicoA[l];
        float d[21];
        #pragma unroll
        for (int i = 0; i < 21; i++) d[i] = 0.f;
        for (int u = t; u < cico; u += 64) {
            float b = b2l[u];
            float w[5];
            #pragma unroll
            for (int k = 0; k < 5; k++) w[k] = w2l[k * cico + u];
            int p = 0;
            #pragma unroll
            for (int k = 0; k < 5; k++) {
                #pragma unroll
                for (int k2 = k; k2 < 5; k2++) d[p++] += w[k] * w[k2];
            }
            #pragma unroll
            for (int k = 0; k < 5; k++) d[15 + k] += b * w[k];
            d[20] += b * b;
        }
        #pragma unroll
        for (int i = 0; i < 21; i++) {
            #pragma unroll
            for (int off = 32; off; off >>= 1) d[i] += __shfl_down(d[i], off);
        }
        if (t == 0) {
            static const int EA[5] = {1048576, 262144, 65536, 16384, 4096};
            const float* H1 = A.H + l * 20;
            const float* H2 = H1 + 5;
            float sq = (float)EA[l] * d[20];
            #pragma unroll
            for (int k = 0; k < 5; k++) sq += 2.f * d[15 + k] * H1[k];
            int p = 0;
            #pragma unroll
            for (int k = 0; k < 5; k++) {
                #pragma unroll
                for (int k2 = k; k2 < 5; k2++) {
                    sq += ((k == k2) ? 1.f : 2.f) * d[p] * H2[p];
                    p++;
                }
            }
            A.sq[l] = sq;
        }
    }
}

// ---------------------------------------------------------------------------
// K3: scatter 4 segs (148) | bucket1 LDS-sort (256)
// ---------------------------------------------------------------------------
__global__ __launch_bounds__(256) void k3_fuseC(GA A)
{
    __shared__ float4 st4[CAP1];                   // 20KB
    __shared__ short  inv[CAP1];                   // 2.5KB
    __shared__ int h64[64], l64[64], c64[64];
    int B = blockIdx.x, t = threadIdx.x;

    if (B < A.sg.tstart[4]) {                      // ---- scatter ----
        int s = 0;
        while (s < 3 && B >= A.sg.tstart[s + 1]) s++;
        int i0 = (B - A.sg.tstart[s]) * 1024;
        const int* idx = A.sg.idx[s];
        int* cnt = A.sg.cnt[s];
        const int* rp = A.sg.rp[s];
        int* out = A.sg.out[s];
        int n = A.sg.n[s];
        #pragma unroll
        for (int j = 0; j < 4; j++) {
            int i = i0 + j * 256 + t;
            if (i < n) {
                int d = idx[i];
                int p = atomicSub(&cnt[d], 1) - 1;
                out[rp[d] + p] = i;
            }
        }
        return;
    }
    B -= A.sg.tstart[4];
    {                                              // ---- bucket1 ----
        int b = B;
        int n = A.bcnt1[b];
        if (n > CAP1) n = CAP1;
        size_t base = (size_t)b * CAP1;
        for (int j = t; j < n; j += 256) st4[j] = A.pay1[base + j];
        if (t < 64) h64[t] = 0;
        __syncthreads();
        for (int j = t; j < n; j += 256) {
            int rel = (int)(__float_as_uint(st4[j].x) >> 16) & 63;
            atomicAdd(&h64[rel], 1);
        }
        __syncthreads();
        if (t < 64) {                              // wave-level exclusive scan
            int v = h64[t];
            int val = v;
            #pragma unroll
            for (int d = 1; d < 64; d <<= 1) {
                int u = __shfl_up(val, d);
                if (t >= d) val += u;
            }
            l64[t] = val - v;
            c64[t] = val - v;
        }
        __syncthreads();
        for (int j = t; j < n; j += 256) {
            int rel = (int)(__float_as_uint(st4[j].x) >> 16) & 63;
            int p = atomicAdd(&c64[rel], 1);
            inv[p] = (short)j;
        }
        __syncthreads();
        int lo = A.bs1[b];
        for (int j = t; j < n; j += 256)           // coalesced sorted write
            A.rec1[lo + j] = st4[inv[j]];
        if (t < 64) A.rp1[(b << 6) + t] = lo + l64[t];
    }
}

// ---------------------------------------------------------------------------
// K4: pool0 (960)
// ---------------------------------------------------------------------------
__global__ __launch_bounds__(256) void k4_pool0(GA A)
{
    int gt = blockIdx.x * 256 + threadIdx.x;
    if (gt >= 16384 * 15) return;
    int c = gt / 15, o = gt - c * 15;
    int r0 = A.sg.rp[3][c], r1 = A.sg.rp[3][c + 1];
    const int* cnid = A.sg.out[3];
    int d = r1 - r0;
    if (o < 12) {
        float m = -INFINITY;
        for (int j = r0; j < r1; j++)
            m = fmaxf(m, A.y0[(size_t)cnid[j] * 12 + o]);
        if (d == 0 || !isfinite(m)) m = 0.f;
        A.xn0[c * 15 + o] = m;
    } else {
        int k = o - 12;
        float sum = 0.f;
        for (int j = r0; j < r1; j++)
            sum += A.pos0[cnid[j] * 3 + k];
        A.xn0[c * 15 + o] = sum / fmaxf((float)d, 1.f);
    }
}

// ---------------------------------------------------------------------------
// K5: conv1 (block/node, streams rec1, plain xn0 input) + pool->raw1
// ---------------------------------------------------------------------------
__global__ __launch_bounds__(256) void k5_conv1(GA A)
{
    constexpr int CI = 15, CO = 20, CH = 48, CICO = CI * CO, RN = 24;
    __shared__ float w1s[20];
    __shared__ float4 recb[CH];
    __shared__ int   svb[CH];
    __shared__ float hb[CH * 6];
    __shared__ float xs[CH * CI];
    __shared__ float Sx[6 * CI];
    __shared__ float xown[CI];

    int t = threadIdx.x, v = blockIdx.x;
    if (t < 20) w1s[t] = (t < 15) ? A.w1[1][t] : A.b1[1][t - 15];
    if (t < CI) xown[t] = A.xn0[v * CI + t];
    int r0 = A.rp1[v], r1 = A.rp1[v + 1];
    int d = r1 - r0;
    float acc = 0.f;

    for (int c0 = r0; c0 < r1; c0 += CH) {
        int cn = min(CH, r1 - c0);
        if (t < cn) {
            float4 R = A.rec1[c0 + t];
            recb[t] = R;
            svb[t]  = (int)(__float_as_uint(R.x) & 0xffffu);
            hb[t * 6] = 1.f;
        }
        __syncthreads();
        if (t < cn * 5) {
            int j = t / 5, k = t % 5;
            float e0 = recb[j].y, e1 = recb[j].z, e2 = recb[j].w;
            hb[j * 6 + 1 + k] =
                ftanh(e0 * w1s[k] + e1 * w1s[5 + k] + e2 * w1s[10 + k] + w1s[15 + k]);
        }
        for (int u = t; u < cn * CI; u += 256) {
            int j = u / CI, i = u - j * CI;
            xs[u] = A.xn0[svb[j] * CI + i];
        }
        __syncthreads();
        if (t < 6 * CI) {
            int i = t / 6, k6 = t - (t / 6) * 6;
            for (int j = 0; j < cn; j++)
                acc += hb[j * 6 + k6] * xs[j * CI + i];
        }
        __syncthreads();
    }

    if (t < 6 * CI) Sx[t] = acc;
    __syncthreads();

    if (t < CO) {
        float m = 0.f;
        const float* w2 = A.w2[1];
        const float* b2 = A.b2[1];
        for (int i = 0; i < CI; i++) {
            m += b2[i * CO + t] * Sx[i * 6];
            #pragma unroll
            for (int k = 0; k < 5; k++)
                m += w2[k * CICO + i * CO + t] * Sx[i * 6 + 1 + k];
        }
        m /= fmaxf((float)d, 1.f);
        for (int i = 0; i < CI; i++) m += xown[i] * A.root[1][i * CO + t];
        m += A.bias[1][t];
        int c = A.cluster[1][v];
        unsigned* orow = A.raw[1] + (size_t)c * RN;
        atomicMax(&orow[t], fenc(m));
        if (t < 3) atomicAdd((float*)&orow[CO + t], xown[CI - 3 + t]);
        if (t == 0) atomicAdd((float*)&orow[CO + 3], 1.f);
    }
}

// ---------------------------------------------------------------------------
// K6-8: coop conv levels 2-4 + fused pool epilogue
// ---------------------------------------------------------------------------
template<int CI, int CO>
__global__ __launch_bounds__(256) void coopP_k(GA A, int l)
{
    constexpr int CH = 48, CICO = CI * CO, RL = CI + 1, RN = CO + 4;
    __shared__ float w1s[20];
    __shared__ int   eb[CH], svb[CH];
    __shared__ float hb[CH * 6];
    __shared__ float xs[CH * CI];
    __shared__ float Sx[6 * CI];
    __shared__ float xown[CI];

    int t = threadIdx.x, v = blockIdx.x;
    int s = l - 2;
    const unsigned* rin = A.raw[l - 1];
    const int* rp = A.sg.rp[s];
    const int* eid = A.sg.out[s];
    const int* src = A.srcE[s];
    const float* eattr = A.eaE[s];

    if (t < 20) w1s[t] = (t < 15) ? A.w1[l][t] : A.b1[l][t - 15];
    if (t < CI) xown[t] = row_val(rin + (size_t)v * RL, t, CI);
    int r0 = rp[v], r1 = rp[v + 1];
    int d = r1 - r0;
    float acc = 0.f;

    for (int c0 = r0; c0 < r1; c0 += CH) {
        int cn = min(CH, r1 - c0);
        if (t < cn) {
            int e = eid[c0 + t];
            eb[t]  = e;
            svb[t] = src[e];
            hb[t * 6] = 1.f;
        }
        __syncthreads();
        if (t < cn * 5) {
            int j = t / 5, k = t % 5;
            int e = eb[j];
            float e0 = eattr[e * 3], e1 = eattr[e * 3 + 1], e2 = eattr[e * 3 + 2];
            hb[j * 6 + 1 + k] =
                ftanh(e0 * w1s[k] + e1 * w1s[5 + k] + e2 * w1s[10 + k] + w1s[15 + k]);
        }
        for (int u = t; u < cn * CI; u += 256) {
            int j = u / CI, i = u - j * CI;
            xs[u] = row_val(rin + (size_t)svb[j] * RL, i, CI);
        }
        __syncthreads();
        if (t < 6 * CI) {
            int i = t / 6, k6 = t - (t / 6) * 6;
            for (int j = 0; j < cn; j++)
                acc += hb[j * 6 + k6] * xs[j * CI + i];
        }
        __syncthreads();
    }

    if (t < 6 * CI) Sx[t] = acc;
    __syncthreads();

    if (t < CO) {
        float m = 0.f;
        const float* w2 = A.w2[l];
        const float* b2 = A.b2[l];
        for (int i = 0; i < CI; i++) {
            m += b2[i * CO + t] * Sx[i * 6];
            #pragma unroll
            for (int k = 0; k < 5; k++)
                m += w2[k * CICO + i * CO + t] * Sx[i * 6 + 1 + k];
        }
        m /= fmaxf((float)d, 1.f);
        for (int i = 0; i < CI; i++) m += xown[i] * A.root[l][i * CO + t];
        m += A.bias[l][t];
        int c = A.cluster[l][v];
        unsigned* orow = A.raw[l] + (size_t)c * RN;
        atomicMax(&orow[t], fenc(m));
        if (t < 3) atomicAdd((float*)&orow[CO + t], xown[CI - 3 + t]);
        if (t == 0) atomicAdd((float*)&orow[CO + 3], 1.f);
    }
}

// ---------------------------------------------------------------------------
// K9: fc (decodes raw[4])
// ---------------------------------------------------------------------------
__global__ __launch_bounds__(128) void k9_fc(GA A)
{
    __shared__ float feat[8 * 376];
    __shared__ float logit[80];
    __shared__ float roff[8];
    const unsigned* r5 = A.raw[4];
    for (int idx = threadIdx.x; idx < 64 * 47; idx += 128) {
        int n = idx / 47, i = idx - n * 47;
        int b = n >> 3, s = n & 7;
        feat[b * 376 + s * 47 + i] = row_val(r5 + (size_t)n * 48, i, 47);
    }
    __syncthreads();
    int t = threadIdx.x;
    if (t < 80) {
        int b = t / 10, j = t % 10;
        float acc = A.fc_b[j];
        for (int k = 0; k < 376; k++) acc += feat[b * 376 + k] * A.fc_w[k * 10 + j];
        logit[t] = acc;
    }
    __syncthreads();
    if (t < 8) {
        float m = -1e30f;
        for (int j = 0; j < 10; j++) m = fmaxf(m, logit[t * 10 + j]);
        float ssum = 0.f;
        for (int j = 0; j < 10; j++) ssum += expf(logit[t * 10 + j] - m);
        roff[t] = m + logf(ssum);
    }
    __syncthreads();
    if (t < 80) A.out[t] = logit[t] - roff[t / 10];
    if (t == 0) {
        const float* sq = A.sq;
        float closs = 0.f;
        closs += sq[0] * (1.0f / 12582912.0f);
        closs += sq[1] * (1.0f / 78643200.0f);
        closs += sq[2] * (1.0f / 42205184.0f);
        closs += sq[3] * (1.0f / 18284544.0f);
        closs += sq[4] * (1.0f / 7028736.0f);
        A.out[80] = closs;
    }
}

// ---------------------------------------------------------------------------

extern "C" void kernel_launch(void* const* d_in, const int* in_sizes, int n_in,
                              void* d_out, int out_size, void* d_ws, size_t ws_size,
                              hipStream_t stream)
{
    static const int NSa[6] = {65536, 16384, 4096, 1024, 256, 64};
    static const int ESa[5] = {1048576, 262144, 65536, 16384, 4096};
    static const int RNa[5] = {16, 24, 32, 40, 48};   // raw row widths (words)

    // ---- workspace layout (words) ----
    int* wsw = (int*)d_ws;
    size_t off = 0;
    auto alw = [&](size_t n) -> size_t {
        size_t p = off; off += (n + 63) & ~(size_t)63; return p;
    };
    // zeroed region
    size_t degO[5];
    for (int l = 2; l < 5; l++) degO[l] = alw(NSa[l]);
    size_t cdeg0O = alw(NSa[1]);                      // cluster0 counts
    size_t HO    = alw(100);
    size_t bcO   = alw(NBK0);
    size_t bc1O  = alw(NBK1);
    size_t rawO[5];
    for (int l = 1; l < 5; l++) rawO[l] = alw((size_t)NSa[l + 1] * RNa[l]);
    size_t zeroWords = off;
    // non-zeroed
    size_t rpO[5], eidO[5];
    for (int l = 2; l < 5; l++) rpO[l]  = alw(NSa[l] + 1);
    size_t crp0O = alw(NSa[1] + 1);
    for (int l = 2; l < 5; l++) eidO[l] = alw(ESa[l]);
    size_t cnid0O = alw(NSa[0]);
    size_t pay2O = alw((size_t)NBK0 * CAP0 * 4);
    size_t y0O   = alw((size_t)NSa[0] * 12);
    size_t xn0O  = alw((size_t)NSa[1] * 15);
    size_t bs1O  = alw(NBK1 + 1);
    size_t pay1O = alw((size_t)NBK1 * CAP1 * 4);
    size_t rec1O = alw((size_t)ESa[1] * 4);
    size_t rp1O  = alw(NSa[1] + 1);
    size_t sqO   = alw(8);

    GA A{};
    A.src0 = (const int*)d_in[2];  A.dst0 = (const int*)d_in[3];
    A.ea0  = (const float*)d_in[4];
    A.src1 = (const int*)d_in[12]; A.dst1 = (const int*)d_in[13];
    A.ea1  = (const float*)d_in[14];
    A.x0   = (const float*)d_in[0];
    A.pos0 = (const float*)d_in[1];
    for (int l = 0; l < 5; l++) {
        A.cluster[l] = (const int*)d_in[5 + 10 * l];
        A.w1[l]   = (const float*)d_in[6 + 10 * l];
        A.b1[l]   = (const float*)d_in[7 + 10 * l];
        A.w2[l]   = (const float*)d_in[8 + 10 * l];
        A.b2[l]   = (const float*)d_in[9 + 10 * l];
        A.root[l] = (const float*)d_in[10 + 10 * l];
        A.bias[l] = (const float*)d_in[11 + 10 * l];
    }
    for (int s = 0; s < 3; s++) {
        A.srcE[s] = (const int*)d_in[2 + 10 * (s + 2)];
        A.eaE[s]  = (const float*)d_in[4 + 10 * (s + 2)];
    }
    A.fc_w = (const float*)d_in[52];
    A.fc_b = (const float*)d_in[53];
    A.bcnt  = wsw + bcO;
    A.bcnt1 = wsw + bc1O;
    A.pay2 = (float4*)(wsw + pay2O);
    A.pay1 = (float4*)(wsw + pay1O);
    A.rec1 = (float4*)(wsw + rec1O);
    A.y0   = (float*)(wsw + y0O);
    A.xn0  = (float*)(wsw + xn0O);
    for (int l = 1; l < 5; l++) A.raw[l] = (unsigned*)(wsw + rawO[l]);
    A.H  = (float*)(wsw + HO);
    A.sq = (float*)(wsw + sqO);
    A.bs1 = wsw + bs1O;
    A.rp1 = wsw + rp1O;
    A.out = (float*)d_out;

    // seg descriptors: 0-2 = edge segs L2-4, 3 = cluster0
    int tiles = 0;
    for (int s = 0; s < 3; s++) {
        int l = s + 2;
        A.sg.idx[s] = (const int*)d_in[3 + 10 * l];
        A.sg.cnt[s] = wsw + degO[l];
        A.sg.rp [s] = wsw + rpO[l];
        A.sg.out[s] = wsw + eidO[l];
        A.sg.n  [s] = ESa[l];
        A.sg.nb [s] = NSa[l];
        A.sg.tstart[s] = tiles;
        tiles += (ESa[l] + 1023) / 1024;
    }
    A.sg.idx[3] = (const int*)d_in[5];              // cluster0
    A.sg.cnt[3] = wsw + cdeg0O;
    A.sg.rp [3] = wsw + crp0O;
    A.sg.out[3] = wsw + cnid0O;
    A.sg.n  [3] = NSa[0];
    A.sg.nb [3] = NSa[1];
    A.sg.tstart[3] = tiles;
    tiles += (NSa[0] + 1023) / 1024;
    A.sg.tstart[4] = tiles;                          // 148

    int hsB = 0;
    A.hb0[0] = 0;
    for (int j = 0; j < 3; j++) {                    // hstats: levels 2-4
        hsB += (ESa[j + 2] + 2047) / 2048;
        A.hb0[j + 1] = hsB;
    }
    A.hsB = hsB;                                     // 42

    hipMemsetAsync(d_ws, 0, zeroWords * 4, stream);

    k1_fuseA<<<NT0 + NT1 + hsB + tiles, 256, 0, stream>>>(A);   // 830
    k2_fuseB<<<NBK0 + 1 + 3 + 1 + 5,    256, 0, stream>>>(A);   // 266
    k3_fuseC<<<tiles + NBK1,            256, 0, stream>>>(A);   // 404
    k4_pool0<<<(16384 * 15 + 255) / 256, 256, 0, stream>>>(A);  // 960
    k5_conv1<<<NSa[1],                  256, 0, stream>>>(A);   // 16384
    coopP_k<23, 28><<<NSa[2],           256, 0, stream>>>(A, 2);
    coopP_k<31, 36><<<NSa[3],           256, 0, stream>>>(A, 3);
    coopP_k<39, 44><<<NSa[4],           256, 0, stream>>>(A, 4);
    k9_fc<<<1, 128, 0, stream>>>(A);
}